// Round 10
// baseline (227.251 us; speedup 1.0000x reference)
//
#include <hip/hip_runtime.h>

#define DD 64
#define SLOTMAX 64

using s8v   = __attribute__((ext_vector_type(8))) short;   // 8 bf16 (4 VGPRs)
using f32x4 = __attribute__((ext_vector_type(4))) float;   // MFMA C/D

typedef unsigned int   uint_t;
typedef unsigned short ushort_t;

union U8 { s8v v; uint_t u[4]; };

__device__ __forceinline__ float silu_f(float x) {
    return x / (1.0f + __expf(-x));
}
__device__ __forceinline__ float clamp100(float x) {
    return fminf(fmaxf(x, -100.0f), 100.0f);
}
__device__ __forceinline__ unsigned short f2bf(float x) {
    unsigned int u = __float_as_uint(x);
    return (unsigned short)((u + 0x7FFFu + ((u >> 16) & 1u)) >> 16);   // RNE
}
__device__ __forceinline__ float bf2f(ushort_t v) {
    return __uint_as_float(((uint_t)v) << 16);
}
__device__ __forceinline__ uint_t cvt_pk_bf16(float lo, float hi) {
    uint_t r;
    asm("v_cvt_pk_bf16_f32 %0, %1, %2" : "=v"(r) : "v"(lo), "v"(hi));
    return r;
}

#define WAVE_FENCE() do { asm volatile("s_waitcnt lgkmcnt(0)" ::: "memory"); \
                          __builtin_amdgcn_sched_barrier(0); } while (0)

// ---------------------------------------------------------------------------
// prep_all sections by blockIdx:
//  [histBlocks): histogram cnt_i[row]++
//  [hbfBlocks):  h (f32) -> bf16
//  [c4Blocks):   coord -> float4 [N,4]
//  [wfBlocks):   weight fragments:
//   mats 0..6, 4096 shorts each; mat7 @28672 (rank-3+be1); mat8 @30720 (be2,bc1)
//   mats 2/3 (We2/Wc1) use REMAPPED k = 16*(2*k0+(i>>2)) + 4*(lane>>4) + (i&3)
// ---------------------------------------------------------------------------
__global__ __launch_bounds__(256) void prep_all(
    const float* __restrict__ h,
    const float* __restrict__ coord,
    const float* __restrict__ We1, const float* __restrict__ We2,
    const float* __restrict__ Wc1,
    const float* __restrict__ Wn1, const float* __restrict__ Wn2,
    const float* __restrict__ be1, const float* __restrict__ be2,
    const float* __restrict__ bc1,
    const int*   __restrict__ ei,
    ushort_t* __restrict__ hbf,
    ushort_t* __restrict__ wf,
    float4* __restrict__ coord4,
    int* __restrict__ cnt_i,
    int N, int E, int total8, int histBlocks, int hbfBlocks, int c4Blocks)
{
    const int b = blockIdx.x;
    if (b < histBlocks) {
        const int e = b * 256 + threadIdx.x;
        if (e < E) atomicAdd(&cnt_i[ei[e]], 1);
    } else if (b < histBlocks + hbfBlocks) {
        const int t = (b - histBlocks) * 256 + threadIdx.x;
        if (t < total8) {
            const float4 v0 = ((const float4*)h)[t * 2 + 0];
            const float4 v1 = ((const float4*)h)[t * 2 + 1];
            uint4 o;
            o.x = (uint_t)f2bf(v0.x) | ((uint_t)f2bf(v0.y) << 16);
            o.y = (uint_t)f2bf(v0.z) | ((uint_t)f2bf(v0.w) << 16);
            o.z = (uint_t)f2bf(v1.x) | ((uint_t)f2bf(v1.y) << 16);
            o.w = (uint_t)f2bf(v1.z) | ((uint_t)f2bf(v1.w) << 16);
            ((uint4*)hbf)[t] = o;
        }
    } else if (b < histBlocks + hbfBlocks + c4Blocks) {
        const int t = (b - histBlocks - hbfBlocks) * 256 + threadIdx.x;
        if (t < N) {
            float4 c;
            c.x = coord[3 * t + 0];
            c.y = coord[3 * t + 1];
            c.z = coord[3 * t + 2];
            c.w = 0.0f;
            coord4[t] = c;
        }
    } else {
        const int t = (b - histBlocks - hbfBlocks - c4Blocks) * 256 + threadIdx.x;
        if (t >= 32768) return;
        if (t < 28672) {
            const int j    = t & 7;
            const int lane = (t >> 3) & 63;
            const int n0   = (t >> 9) & 3;
            const int k0   = (t >> 11) & 1;
            const int mat  = t >> 12;
            const int g    = lane >> 4;
            int k;
            if (mat == 2 || mat == 3) k = 16 * (2 * k0 + (j >> 2)) + 4 * g + (j & 3);
            else                      k = k0 * 32 + g * 8 + j;
            const int n = n0 * 16 + (lane & 15);
            float v;
            if      (mat == 0) v = We1[(size_t)k * 64 + n];
            else if (mat == 1) v = We1[(size_t)(64 + k) * 64 + n];
            else if (mat == 2) v = We2[(size_t)k * 64 + n];
            else if (mat == 3) v = Wc1[(size_t)k * 64 + n];
            else if (mat == 4) v = Wn1[(size_t)k * 64 + n];
            else if (mat == 5) v = Wn1[(size_t)(64 + k) * 64 + n];
            else               v = Wn2[(size_t)k * 64 + n];
            wf[t] = f2bf(v);
        } else {
            const int t2   = t - 28672;
            const int j    = t2 & 7;
            const int lane = (t2 >> 3) & 63;
            const int n0   = (t2 >> 9) & 3;
            const int xm   = (t2 >> 11) & 1;
            const int k = 8 * (lane >> 4) + j;
            const int m = n0 * 16 + (lane & 15);
            float v = 0.0f;
            if (xm == 0) {
                if      (k == 0) v = We1[(size_t)128 * 64 + m];
                else if (k == 1) v = We1[(size_t)129 * 64 + m];
                else if (k == 2) v = We1[(size_t)130 * 64 + m];
                else if (k == 3) v = be1[m];
            } else {
                if      (k == 0) v = be2[m];
                else if (k == 1) v = bc1[m];
            }
            wf[t] = f2bf(v);
        }
    }
}

// ---------------------------------------------------------------------------
// prep_scan: nstart[n] = exclusive prefix of min(deg,64); block-local scan +
// one atomic block-base on cursor (global order arbitrary; per-node ranges
// contiguous regardless). cursor ends at P = total positions.
// ---------------------------------------------------------------------------
__global__ __launch_bounds__(256) void prep_scan(
    const int* __restrict__ cnt_i,
    int* __restrict__ cursor,
    int* __restrict__ nstart,
    int N)
{
    __shared__ int sdata[256];
    __shared__ int sbase;
    const int tid = threadIdx.x;
    const int n = blockIdx.x * 256 + tid;
    int deg = 0;
    if (n < N) { deg = cnt_i[n]; if (deg > SLOTMAX) deg = SLOTMAX; }
    sdata[tid] = deg;
    __syncthreads();
    for (int off = 1; off < 256; off <<= 1) {
        const int t = (tid >= off) ? sdata[tid - off] : 0;
        __syncthreads();
        sdata[tid] += t;
        __syncthreads();
    }
    if (tid == 255) sbase = atomicAdd(cursor, sdata[255]);
    __syncthreads();
    if (n < N) nstart[n] = sbase + sdata[tid] - deg;
}

// ---------------------------------------------------------------------------
// prep_fill: counting-sort scatter. eperm4[nstart[row]+s] = {row, col, eaPack}
// (eaPack = bf16(ea0) | bf16(ea1)<<16).
// ---------------------------------------------------------------------------
__global__ __launch_bounds__(256) void prep_fill(
    const int* __restrict__ ei,
    const float* __restrict__ ea,
    const int* __restrict__ nstart,
    int* __restrict__ cnt2,
    int4* __restrict__ eperm4,
    int E)
{
    const int e = blockIdx.x * 256 + threadIdx.x;
    if (e >= E) return;
    const int r = ei[e];
    const int s = atomicAdd(&cnt2[r], 1);
    if (s < SLOTMAX) {
        const int c = ei[E + e];
        const float2 a2 = *(const float2*)(ea + 2 * (size_t)e);
        const uint_t pk = cvt_pk_bf16(a2.x, a2.y);
        int4 v; v.x = r; v.y = c; v.z = (int)pk; v.w = 0;
        eperm4[(size_t)nstart[r] + s] = v;
    }
}

// ---------------------------------------------------------------------------
// Edge kernel, POSITION-MAJOR over the sorted edge list: one wave per 16
// consecutive positions. One coalesced int4 load replaces all index chains;
// row-side gathers are ~wave-uniform (sorted by row) -> L1 hits.
// Writes edge_feat[pos] and trans4[pos] (contiguous per node for agg).
// ---------------------------------------------------------------------------
__global__ __launch_bounds__(512, 4) void egcl_edge(
    const ushort_t* __restrict__ hbf,
    const ushort_t* __restrict__ wfG,
    const float4* __restrict__ coord4,
    const int4* __restrict__ eperm4,
    const int* __restrict__ cursorP,
    const float* __restrict__ Wc2,
    uint_t* __restrict__ efu,        // edge_feat as u32 pairs [P][32]
    float4* __restrict__ trans4,     // [P]
    int totalWaves)
{
    __shared__ ushort_t fragLDS[20480];   // mats 0..3 + mat7 + mat8 = 40 KB

    const int tid = threadIdx.x;
    #pragma unroll
    for (int i = 0; i < 4; ++i)
        ((uint4*)fragLDS)[tid + i * 512] = ((const uint4*)wfG)[tid + i * 512];
    ((uint4*)fragLDS)[2048 + tid] = ((const uint4*)wfG)[3584 + tid];
    __syncthreads();

    const int P = cursorP[0];
    const int wid  = tid >> 6;
    const int lane = tid & 63;
    const int l15  = lane & 15;
    const int g    = lane >> 4;

#define LD_W(mat, k0, m0) \
    (*(const s8v*)(fragLDS + ((((mat)*2 + (k0))*4 + (m0)) * 512) + lane * 8))
#define LD_X7(m0) (*(const s8v*)(fragLDS + 16384 + (m0) * 512 + lane * 8))
#define LD_XB(m0) (*(const s8v*)(fragLDS + 18432 + (m0) * 512 + lane * 8))

    float wc2_c[4][4];
    #pragma unroll
    for (int m0 = 0; m0 < 4; ++m0)
        #pragma unroll
        for (int j = 0; j < 4; ++j)
            wc2_c[m0][j] = Wc2[m0 * 16 + 4 * g + j];

    U8 b2f, bcf;   // constant bias-selector B fragments
    b2f.u[0] = 0x00003F80u; b2f.u[1] = 0; b2f.u[2] = 0; b2f.u[3] = 0;  // [1,0,..]
    bcf.u[0] = 0x3F800000u; bcf.u[1] = 0; bcf.u[2] = 0; bcf.u[3] = 0;  // [0,1,..]

    const f32x4 zero4 = {0.f, 0.f, 0.f, 0.f};

    for (int t = blockIdx.x * 8 + wid; t * 16 < P; t += totalWaves) {
        const int p   = t * 16 + l15;
        const bool val = (p < P);
        const int pL  = val ? p : (P - 1);

        const int4 e4 = eperm4[pL];
        const int row = e4.x;
        const int col = e4.y;
        const uint_t eap = (uint_t)e4.z;

        const float4 cr = coord4[row];
        const float4 cc = coord4[col];
        const ushort_t* hr = hbf + (size_t)row * 64;
        const ushort_t* hc = hbf + (size_t)col * 64;
        const s8v br0 = *(const s8v*)(hr + g * 8);
        const s8v br1 = *(const s8v*)(hr + 32 + g * 8);
        const s8v bc0 = *(const s8v*)(hc + g * 8);
        const s8v bc1 = *(const s8v*)(hc + 32 + g * 8);

        const float dx = cr.x - cc.x, dy = cr.y - cc.y, dz = cr.z - cc.z;
        const float radial = dx * dx + dy * dy + dz * dz;

        U8 ex;   // extra k-block input: [radial, ea0, ea1, 1]
        const float ea0f = __uint_as_float(eap << 16);
        ex.u[0] = cvt_pk_bf16(radial, ea0f);
        ex.u[1] = (eap >> 16) | 0x3F800000u;   // [bf(ea1), bf(1.0)]
        ex.u[2] = 0; ex.u[3] = 0;

        // ---- layer 1: row-half + col-half + rank3 ----
        f32x4 c1[4];
        #pragma unroll
        for (int m0 = 0; m0 < 4; ++m0) {
            f32x4 a = zero4;
            a = __builtin_amdgcn_mfma_f32_16x16x32_bf16(LD_W(0, 0, m0), br0, a, 0, 0, 0);
            a = __builtin_amdgcn_mfma_f32_16x16x32_bf16(LD_W(0, 1, m0), br1, a, 0, 0, 0);
            a = __builtin_amdgcn_mfma_f32_16x16x32_bf16(LD_W(1, 0, m0), bc0, a, 0, 0, 0);
            a = __builtin_amdgcn_mfma_f32_16x16x32_bf16(LD_W(1, 1, m0), bc1, a, 0, 0, 0);
            a = __builtin_amdgcn_mfma_f32_16x16x32_bf16(LD_X7(m0),      ex.v, a, 0, 0, 0);
            c1[m0] = a;
        }

        // silu + in-register repack to next layer's B fragment
        U8 f2a, f2b;
        #pragma unroll
        for (int m0 = 0; m0 < 4; ++m0) {
            const float ya = silu_f(c1[m0][0]);
            const float yb = silu_f(c1[m0][1]);
            const float yc = silu_f(c1[m0][2]);
            const float yd = silu_f(c1[m0][3]);
            U8& dst = (m0 < 2) ? f2a : f2b;
            dst.u[(m0 & 1) * 2 + 0] = cvt_pk_bf16(ya, yb);
            dst.u[(m0 & 1) * 2 + 1] = cvt_pk_bf16(yc, yd);
        }

        // ---- layer 2 (edge_feat) ----
        f32x4 c2[4];
        #pragma unroll
        for (int m0 = 0; m0 < 4; ++m0) {
            f32x4 a = zero4;
            a = __builtin_amdgcn_mfma_f32_16x16x32_bf16(LD_W(2, 0, m0), f2a.v, a, 0, 0, 0);
            a = __builtin_amdgcn_mfma_f32_16x16x32_bf16(LD_W(2, 1, m0), f2b.v, a, 0, 0, 0);
            a = __builtin_amdgcn_mfma_f32_16x16x32_bf16(LD_XB(m0),      b2f.v, a, 0, 0, 0);
            c2[m0] = a;
        }

        // silu, store edge_feat, build coord-head fragments
        uint_t* efrow = efu + (size_t)pL * 32;
        U8 f3a, f3b;
        #pragma unroll
        for (int m0 = 0; m0 < 4; ++m0) {
            const float ya = silu_f(c2[m0][0]);
            const float yb = silu_f(c2[m0][1]);
            const float yc = silu_f(c2[m0][2]);
            const float yd = silu_f(c2[m0][3]);
            const uint_t p0 = cvt_pk_bf16(ya, yb);
            const uint_t p1 = cvt_pk_bf16(yc, yd);
            U8& dst = (m0 < 2) ? f3a : f3b;
            dst.u[(m0 & 1) * 2 + 0] = p0;
            dst.u[(m0 & 1) * 2 + 1] = p1;
            if (val) {
                uint2 st; st.x = p0; st.y = p1;
                *(uint2*)(efrow + m0 * 8 + g * 2) = st;   // dims 16m0+4g..+3
            }
        }

        // ---- coord head: 64 -> 64 -> 1 ----
        float pacc = 0.f;
        #pragma unroll
        for (int m0 = 0; m0 < 4; ++m0) {
            f32x4 a = zero4;
            a = __builtin_amdgcn_mfma_f32_16x16x32_bf16(LD_W(3, 0, m0), f3a.v, a, 0, 0, 0);
            a = __builtin_amdgcn_mfma_f32_16x16x32_bf16(LD_W(3, 1, m0), f3b.v, a, 0, 0, 0);
            a = __builtin_amdgcn_mfma_f32_16x16x32_bf16(LD_XB(m0),      bcf.v, a, 0, 0, 0);
            #pragma unroll
            for (int j = 0; j < 4; ++j)
                pacc = fmaf(silu_f(a[j]), wc2_c[m0][j], pacc);
        }
        pacc += __shfl_xor(pacc, 16, 64);   // reduce over the 4 g-lanes
        pacc += __shfl_xor(pacc, 32, 64);

        if (val && g == 0) {
            float4 tr;
            tr.x = clamp100(dx * pacc);
            tr.y = clamp100(dy * pacc);
            tr.z = clamp100(dz * pacc);
            tr.w = 0.0f;
            trans4[p] = tr;
        }
    }
#undef LD_W
#undef LD_X7
#undef LD_XB
}

// ---------------------------------------------------------------------------
// Aggregation kernel: one WAVE per node; its edge_feat rows are CONTIGUOUS
// [nstart, nstart+eff) -> pure streaming. Lane layout: 4 edges/iter, lane =
// (sub=l>>4 edge, dp=l&15 dim-quad), uint2 per lane. trans4 likewise.
// ---------------------------------------------------------------------------
__global__ __launch_bounds__(256) void egcl_agg(
    const ushort_t* __restrict__ efbf,
    const float4* __restrict__ trans4,
    const int* __restrict__ nstart,
    const int* __restrict__ cnt_i,
    const float4* __restrict__ coord4,
    ushort_t* __restrict__ aggbf,
    float* __restrict__ coord_out,
    int N)
{
    const int wid  = threadIdx.x >> 6;
    const int lane = threadIdx.x & 63;
    const int n = blockIdx.x * 4 + wid;
    if (n >= N) return;

    const int deg = cnt_i[n];
    const int eff = deg < SLOTMAX ? deg : SLOTMAX;
    const int p0  = nstart[n];

    const int sub = lane >> 4;    // edge subgroup 0..3
    const int dp  = lane & 15;    // dim quad 0..15 (dims 4dp..4dp+3)

    float ax = 0.f, ay = 0.f, az = 0.f, aw = 0.f;
    for (int s = sub; s < eff; s += 4) {
        const uint2 v = *(const uint2*)(efbf + (size_t)(p0 + s) * 64 + dp * 4);
        ax += __uint_as_float(v.x << 16);
        ay += __uint_as_float(v.x & 0xFFFF0000u);
        az += __uint_as_float(v.y << 16);
        aw += __uint_as_float(v.y & 0xFFFF0000u);
    }
    ax += __shfl_xor(ax, 16, 64); ay += __shfl_xor(ay, 16, 64);
    az += __shfl_xor(az, 16, 64); aw += __shfl_xor(aw, 16, 64);
    ax += __shfl_xor(ax, 32, 64); ay += __shfl_xor(ay, 32, 64);
    az += __shfl_xor(az, 32, 64); aw += __shfl_xor(aw, 32, 64);
    if (sub == 0) {
        uint2 st;
        st.x = cvt_pk_bf16(ax, ay);
        st.y = cvt_pk_bf16(az, aw);
        *(uint2*)(aggbf + (size_t)n * 64 + dp * 4) = st;
    }

    float tx = 0.f, ty = 0.f, tz = 0.f;
    for (int s = lane; s < eff; s += 64) {
        const float4 tr = trans4[p0 + s];
        tx += tr.x; ty += tr.y; tz += tr.z;
    }
    #pragma unroll
    for (int msk = 1; msk < 64; msk <<= 1) {
        tx += __shfl_xor(tx, msk, 64);
        ty += __shfl_xor(ty, msk, 64);
        tz += __shfl_xor(tz, msk, 64);
    }
    if (lane == 0) {
        const float inv = 1.0f / fmaxf((float)deg, 1.0f);
        const float4 cn = coord4[n];
        coord_out[(size_t)n * 3 + 0] = cn.x + tx * inv;
        coord_out[(size_t)n * 3 + 1] = cn.y + ty * inv;
        coord_out[(size_t)n * 3 + 2] = cn.z + tz * inv;
    }
}

// ---------------------------------------------------------------------------
// Node kernel: one wave per 16 nodes, MFMA over [h||agg] (K=128) -> 64 -> 64.
// ---------------------------------------------------------------------------
__global__ __launch_bounds__(512, 4) void egcl_node(
    const ushort_t* __restrict__ hbf,
    const ushort_t* __restrict__ aggbf,
    const ushort_t* __restrict__ wfG,   // node mats at +16384
    const float* __restrict__ h,
    const float* __restrict__ bn1,
    const float* __restrict__ bn2,
    float* __restrict__ h_out,
    int N)
{
    __shared__ ushort_t fragLDS[12288];      // mats 4..6, 24 KB
    __shared__ ushort_t ldsY[8][16 * 72];

    const int tid = threadIdx.x;
    #pragma unroll
    for (int i = 0; i < 3; ++i)
        ((uint4*)fragLDS)[tid + i * 512] = ((const uint4*)(wfG + 16384))[tid + i * 512];
    __syncthreads();

    const int wid  = tid >> 6;
    const int lane = tid & 63;
    const int l15  = lane & 15;
    const int g    = lane >> 4;

#define LD_WN(mat, k0, n0) \
    (*(const s8v*)(fragLDS + ((((mat)*2 + (k0))*4 + (n0)) * 512) + lane * 8))

    float bn1_c[4], bn2_c[4];
    #pragma unroll
    for (int n0 = 0; n0 < 4; ++n0) {
        bn1_c[n0] = bn1[n0 * 16 + l15];
        bn2_c[n0] = bn2[n0 * 16 + l15];
    }

    const int wg = blockIdx.x * 8 + wid;
    const int nb = wg * 16;
    if (nb >= N) return;

    const int nod  = nb + l15;
    const int nodL = nod < N ? nod : N - 1;
    const ushort_t* hrow = hbf   + (size_t)nodL * 64;
    const ushort_t* arow = aggbf + (size_t)nodL * 64;
    const s8v aH0 = *(const s8v*)(hrow + g * 8);
    const s8v aH1 = *(const s8v*)(hrow + 32 + g * 8);
    const s8v aG0 = *(const s8v*)(arow + g * 8);
    const s8v aG1 = *(const s8v*)(arow + 32 + g * 8);

    ushort_t* yw = ldsY[wid];
    #pragma unroll
    for (int n0 = 0; n0 < 4; ++n0) {
        f32x4 a = {0.f, 0.f, 0.f, 0.f};
        a = __builtin_amdgcn_mfma_f32_16x16x32_bf16(aH0, LD_WN(0, 0, n0), a, 0, 0, 0);
        a = __builtin_amdgcn_mfma_f32_16x16x32_bf16(aH1, LD_WN(0, 1, n0), a, 0, 0, 0);
        a = __builtin_amdgcn_mfma_f32_16x16x32_bf16(aG0, LD_WN(1, 0, n0), a, 0, 0, 0);
        a = __builtin_amdgcn_mfma_f32_16x16x32_bf16(aG1, LD_WN(1, 1, n0), a, 0, 0, 0);
        #pragma unroll
        for (int jj = 0; jj < 4; ++jj)
            yw[(g * 4 + jj) * 72 + n0 * 16 + l15] = f2bf(silu_f(a[jj] + bn1_c[n0]));
    }
    WAVE_FENCE();

    const ushort_t* yrow = yw + l15 * 72;
    const s8v b0 = *(const s8v*)(yrow + g * 8);
    const s8v b1 = *(const s8v*)(yrow + 32 + g * 8);
    #pragma unroll
    for (int n0 = 0; n0 < 4; ++n0) {
        f32x4 a = {0.f, 0.f, 0.f, 0.f};
        a = __builtin_amdgcn_mfma_f32_16x16x32_bf16(b0, LD_WN(2, 0, n0), a, 0, 0, 0);
        a = __builtin_amdgcn_mfma_f32_16x16x32_bf16(b1, LD_WN(2, 1, n0), a, 0, 0, 0);
        #pragma unroll
        for (int jj = 0; jj < 4; ++jj) {
            const int m = nb + g * 4 + jj;
            if (m < N) {
                const size_t idx = (size_t)m * 64 + n0 * 16 + l15;
                h_out[idx] = h[idx] + (a[jj] + bn2_c[n0]);
            }
        }
    }
#undef LD_WN
}

extern "C" void kernel_launch(void* const* d_in, const int* in_sizes, int n_in,
                              void* d_out, int out_size, void* d_ws, size_t ws_size,
                              hipStream_t stream) {
    const float* h     = (const float*)d_in[0];
    const float* coord = (const float*)d_in[1];
    const int*   ei    = (const int*)  d_in[2];
    const float* ea    = (const float*)d_in[3];
    const float* We1   = (const float*)d_in[4];
    const float* be1   = (const float*)d_in[5];
    const float* We2   = (const float*)d_in[6];
    const float* be2   = (const float*)d_in[7];
    const float* Wn1   = (const float*)d_in[8];
    const float* bn1   = (const float*)d_in[9];
    const float* Wn2   = (const float*)d_in[10];
    const float* bn2   = (const float*)d_in[11];
    const float* Wc1   = (const float*)d_in[12];
    const float* bc1   = (const float*)d_in[13];
    const float* Wc2   = (const float*)d_in[14];

    const int N = in_sizes[0] / DD;     // h is [N,64]
    const int E = in_sizes[3] / 2;      // edge_attr is [E,2]

    float* out       = (float*)d_out;
    float* h_out     = out;
    float* coord_out = out + (size_t)N * DD;

    // workspace layout (16B aligned); total ~142 MB
    char* base = (char*)d_ws;
    ushort_t* hbf   = (ushort_t*)base;                              // N*64*2 B
    const size_t o_wf    = (size_t)N * DD * 2;
    ushort_t* wf    = (ushort_t*)(base + o_wf);                     // 32768*2 B
    const size_t o_agg   = o_wf + 32768 * 2;
    ushort_t* aggbf = (ushort_t*)(base + o_agg);                    // N*64*2 B
    const size_t o_c4    = o_agg + (size_t)N * DD * 2;
    float4* coord4  = (float4*)(base + o_c4);                       // N*16 B
    const size_t o_cnt   = o_c4 + (size_t)N * 16;
    int* cnt_i      = (int*)(base + o_cnt);                         // N ints
    int* cnt2       = cnt_i + N;                                    // N ints
    int* cursor     = cnt_i + 2 * N;                                // 4 ints
    int* nstart     = cnt_i + 2 * N + 4;                            // N ints
    const size_t o_ep    = o_cnt + ((size_t)3 * N + 4) * 4 + 8;     // pad to 16B
    int4* eperm4    = (int4*)(base + ((o_ep + 15) & ~(size_t)15));  // E*16 B
    const size_t o_tr    = ((o_ep + 15) & ~(size_t)15) + (size_t)E * 16;
    float4* trans4  = (float4*)(base + o_tr);                       // E*16 B
    const size_t o_ef    = o_tr + (size_t)E * 16;
    ushort_t* efbf  = (ushort_t*)(base + o_ef);                     // E*64*2 B

    // zero cnt_i, cnt2, cursor in one memset
    hipMemsetAsync((void*)cnt_i, 0, ((size_t)2 * N + 4) * 4, stream);

    // prep: hist | h->bf16 | coord4 | weight frags
    const int histBlocks = (E + 255) / 256;
    const int total8     = N * DD / 8;
    const int hbfBlocks  = (total8 + 255) / 256;
    const int c4Blocks   = (N + 255) / 256;
    const int wfBlocks   = (32768 + 255) / 256;
    prep_all<<<histBlocks + hbfBlocks + c4Blocks + wfBlocks, 256, 0, stream>>>(
        h, coord, We1, We2, Wc1, Wn1, Wn2, be1, be2, bc1, ei,
        hbf, wf, coord4, cnt_i, N, E, total8,
        histBlocks, hbfBlocks, c4Blocks);

    // scan: nstart + total P (in cursor)
    prep_scan<<<(N + 255) / 256, 256, 0, stream>>>(cnt_i, cursor, nstart, N);

    // fill: counting-sort scatter of {row, col, eaPack}
    prep_fill<<<(E + 255) / 256, 256, 0, stream>>>(ei, ea, nstart, cnt2, eperm4, E);

    // edge: position-major tiles of 16, persistent 1024x512
    const int eblocks = 1024;
    const int totalWaves = eblocks * 8;
    egcl_edge<<<eblocks, 512, 0, stream>>>(
        hbf, wf, coord4, eperm4, cursor, Wc2,
        (uint_t*)efbf, trans4, totalWaves);

    // aggregation: one wave per node, streaming contiguous ranges
    const int ablocks = (N + 3) / 4;
    egcl_agg<<<ablocks, 256, 0, stream>>>(
        efbf, trans4, nstart, cnt_i, coord4, aggbf, coord_out, N);

    // node MLP: one wave per 16 nodes
    const int nwaves  = (N + 15) / 16;
    const int nblocks = (nwaves + 7) / 8;
    egcl_node<<<nblocks, 512, 0, stream>>>(
        hbf, aggbf, wf, h, bn1, bn2, h_out, N);
}